// Round 7
// baseline (318.629 us; speedup 1.0000x reference)
//
#include <hip/hip_runtime.h>
#include <hip/hip_fp16.h>
#include <math.h>

// x [64,3,224,224] fp32; expert: conv3x3 s2 (3->64)+ReLU -> conv3x3 s2 (64->128)
// +ReLU -> GAP -> FC 128->2; blend on t softmax conf <= 0.9. Out: 129 floats.
// SAME s2: pad_lo=0, pad_hi=1 both convs. conv2 output 56x56 (GAP/3136).
//
// Round-12: conv1+conv2 FUSED. Block (U 0..27, b, e) = conv2 out rows {2U,2U+1}.
// Needs h1 rows 4U..4U+4 (5 rows x 113 x 64ch = 72.3KB) -> produced in LDS:
//   stage x rows 8U..8U+10 packed f16 (15KB) -> conv1 MFMA (35 tiles, 4 waves
//   round-robin) writes hs in the swizzled layout conv2 reads -> ONE barrier ->
//   round-6 conv2 body unchanged. Deletes the h1 HBM round-trip (209MB write +
//   ~130MB read = ~54us) + one kernel launch. LDS 87.4KB -> 1 block/CU;
//   per-block serial path ~9k cyc x 14 batches ~ 40-60us model.
// hs swizzle: granule g of col c stored at g^(c&7) (bank-uniform, 8 lanes per
// 4-bank group on both write and read = wave64 minimum).
// h1 channel slot = q*16+m*4+reg; w2frag bakes the inverse (icp).
//
// ws layout (bytes):
//   W2B_OFF: ushort(f16) w2frag[2 e][8 octile][18 kc][64 lane][8]
//   W1F_OFF: ushort(f16) w1frag[2 e][4 m][64 lane][8]
//   G_OFF:   float  g[2 e][64 b][128 oc]

#define W2B_OFF   0ull
#define W1F_OFF   294912ull
#define G_OFF     303104ull
#define WS_NEED   (G_OFF + 65536ull + 4096ull)

typedef __attribute__((ext_vector_type(8))) short bf16x8;   // raw 16B chunk
typedef __attribute__((ext_vector_type(8))) _Float16 half8;
typedef __attribute__((ext_vector_type(4))) float f32x4;

__device__ inline ushort f2h(float v) {
  __half h = __float2half(v);            // v_cvt_f16_f32 (RNE)
  return *(ushort*)&h;
}

__global__ __launch_bounds__(256) void prep_new(
    const float* __restrict__ w2_t, const float* __restrict__ w2_f,
    const float* __restrict__ w1_t, const float* __restrict__ w1_f,
    char* __restrict__ ws) {
  int idx = blockIdx.x * 256 + threadIdx.x;
  ushort* w2frag = (ushort*)(ws + W2B_OFF);
  ushort* w1frag = (ushort*)(ws + W1F_OFF);
  if (idx < 147456) {
    int j    = idx & 7;
    int lane = (idx >> 3) & 63;
    int t2   = idx >> 9;          // [0,288)
    int kc   = t2 % 18;
    int t3   = t2 / 18;           // [0,16)
    int octile = t3 & 7;
    int e    = t3 >> 3;
    int oc = octile * 16 + (lane & 15);
    int kk = kc * 32 + (lane >> 4) * 8 + j;
    int kh = kk / 192, r2 = kk - kh * 192, kw = r2 >> 6, slot = r2 & 63;
    // conv1 stores oc m*16+4q+reg at h1 slot q*16+m*4+reg -> invert here:
    int icp = ((slot >> 2) & 3) * 16 + ((slot >> 4) & 3) * 4 + (slot & 3);
    const float* src = e ? w2_f : w2_t;
    w2frag[idx] = f2h(src[((oc * 64 + icp) * 3 + kh) * 3 + kw]);
  } else if (idx < 147456 + 4096) {
    // w1frag: i2 = e*2048 + m*512 + lane*8 + j
    int i2   = idx - 147456;
    int j    = i2 & 7;
    int lane = (i2 >> 3) & 63;
    int m    = (i2 >> 9) & 3;
    int e    = (i2 >> 11) & 1;
    int oc = m * 16 + (lane & 15);
    int kk = (lane >> 4) * 8 + j;
    const float* src = e ? w1_f : w1_t;
    w1frag[i2] = f2h((kk < 27) ? src[oc * 27 + kk] : 0.f);
  }
}

// Fused conv1+conv2. Block (U, b, e); 4 waves; 1 block/CU (87.4KB LDS).
__global__ __launch_bounds__(256, 1) void fused12(
    const float* __restrict__ x,
    const ushort* __restrict__ w1f_all,
    const ushort* __restrict__ w2frag,
    const float* __restrict__ b1_t, const float* __restrict__ b1_f,
    const float* __restrict__ b2_t, const float* __restrict__ b2_f,
    float* __restrict__ g)
{
  const int U = blockIdx.x;     // conv2 out rows {2U, 2U+1}
  const int b = blockIdx.y;
  const int e = blockIdx.z;
  const int tid  = threadIdx.x;
  const int w    = tid >> 6;
  const int lane = tid & 63;
  const int q    = lane >> 4;
  const int n    = lane & 15;
  const int pxl  = lane & 7;
  const int rl   = (lane >> 3) & 1;

  __shared__ ushort hs[5 * 113 * 64];   // 72320 B, h1 rows 4U..4U+4 (swizzled)
  __shared__ ushort xs[3 * 11 * 228];   // 15048 B, x rows 8U..8U+10 packed f16

  const float* b1 = e ? b1_f : b1_t;
  const float* b2 = e ? b2_f : b2_t;

  // ---- preload all conv2 A fragments (L2 latency hides under stage+conv1) ----
  half8 afr[2][18];
#pragma unroll
  for (int mt = 0; mt < 2; ++mt)
#pragma unroll
    for (int kc = 0; kc < 18; ++kc)
      afr[mt][kc] = *(const half8*)
          &w2frag[((size_t)((e * 8 + 2 * w + mt) * 18 + kc)) * 512 + lane * 8];

  // ---- conv1 weights + biases ----
  half8 wf[4];
#pragma unroll
  for (int m = 0; m < 4; ++m)
    wf[m] = *(const half8*)&w1f_all[(((size_t)(e * 4 + m)) * 64 + lane) * 8];
  float4 bv1[4];
#pragma unroll
  for (int m = 0; m < 4; ++m)
    bv1[m] = *(const float4*)&b1[m * 16 + 4 * q];

  // ---- stage x rows 8U..8U+10, cols 0..223, packed f16 (row stride 228) ----
  const float* xb = x + (size_t)b * 150528;
  for (int i = tid; i < 1848; i += 256) {   // 3 ic x 11 rows x 56 float4-units
    int ic  = i / 616;
    int rem = i - ic * 616;
    int r   = rem / 56;
    int u   = rem - r * 56;
    int xr  = 8 * U + r;
    float4 p = make_float4(0.f, 0.f, 0.f, 0.f);
    if (xr < 224) p = *(const float4*)(xb + (ic * 224 + xr) * 224 + 4 * u);
    uint2 uu;
    uu.x = (unsigned int)f2h(p.x) | ((unsigned int)f2h(p.y) << 16);
    uu.y = (unsigned int)f2h(p.z) | ((unsigned int)f2h(p.w) << 16);
    *(uint2*)&xs[(ic * 11 + r) * 228 + 4 * u] = uu;
  }
  if (tid < 33) *(unsigned int*)&xs[tid * 228 + 224] = 0;  // SAME pad col 224
  if (tid < 40) {                                          // h1 pad col 112 = 0
    uint4 z = make_uint4(0, 0, 0, 0);
    *(uint4*)&hs[((tid >> 3) * 113 + 112) * 64 + 8 * (tid & 7)] = z;
  }
  __syncthreads();

  // ---- conv1: 35 tiles (s 0..4 h1-row, nt 0..6 col-tile), wave w: t%4==w ----
  int off1[8];
#pragma unroll
  for (int j = 0; j < 8; ++j) {
    int kk = q * 8 + j;                   // k = ic*9 + kh*3 + kw
    if (kk < 27) {
      int ic = kk / 9, r9 = kk - 9 * ic, kh = r9 / 3, kw = r9 - 3 * kh;
      off1[j] = (ic * 11 + kh) * 228 + kw;
    } else {
      off1[j] = -1;
    }
  }
  for (int t = w; t < 35; t += 4) {
    int s  = t / 7, nt = t - 7 * s;
    int c  = 16 * nt + n;                 // h1 col, < 112
    int bo = 456 * s + 2 * c;             // + local x row 2s, col 2c
    union { half8 h; ushort us[8]; } bh;
#pragma unroll
    for (int j = 0; j < 8; ++j)
      bh.us[j] = (off1[j] >= 0) ? xs[off1[j] + bo] : (ushort)0;
    f32x4 a1[4];
#pragma unroll
    for (int m = 0; m < 4; ++m) a1[m] = (f32x4){0.f, 0.f, 0.f, 0.f};
#pragma unroll
    for (int m = 0; m < 4; ++m)
      a1[m] = __builtin_amdgcn_mfma_f32_16x16x32_f16(wf[m], bh.h, a1[m], 0, 0, 0);
    const bool live = (4 * U + s) < 112;  // h1 row 112 is conv2's zero pad
    union { ushort us[16]; uint4 v4[2]; } pk;
#pragma unroll
    for (int m = 0; m < 4; ++m) {
      pk.us[m * 4 + 0] = f2h(live ? fmaxf(a1[m][0] + bv1[m].x, 0.f) : 0.f);
      pk.us[m * 4 + 1] = f2h(live ? fmaxf(a1[m][1] + bv1[m].y, 0.f) : 0.f);
      pk.us[m * 4 + 2] = f2h(live ? fmaxf(a1[m][2] + bv1[m].z, 0.f) : 0.f);
      pk.us[m * 4 + 3] = f2h(live ? fmaxf(a1[m][3] + bv1[m].w, 0.f) : 0.f);
    }
    // slot = q*16+m*4+reg -> granules 2q, 2q+1; swizzle g^(c&7)
    int colb = (s * 113 + c) * 64;
    *(uint4*)&hs[colb + 8 * ((2 * q)     ^ (c & 7))] = pk.v4[0];
    *(uint4*)&hs[colb + 8 * ((2 * q + 1) ^ (c & 7))] = pk.v4[1];
  }
  __syncthreads();

  // ---- conv2 (round-6 body): wave w -> octiles {2w,2w+1}, 7 N-tiles ----
  f32x4 acc[2][7];
#pragma unroll
  for (int mt = 0; mt < 2; ++mt)
#pragma unroll
    for (int nt = 0; nt < 7; ++nt) acc[mt][nt] = (f32x4){0.f, 0.f, 0.f, 0.f};

#pragma unroll
  for (int kh = 0; kh < 3; ++kh) {
    const int rbase = (kh + 2 * rl) * 113 * 64;   // local h1 row = kh+2*rl
#pragma unroll
    for (int kw = 0; kw < 3; ++kw) {
#pragma unroll
      for (int icc = 0; icc < 2; ++icc) {
        const int kc = kh * 6 + kw * 2 + icc;
        const int gsw = 8 * ((icc * 4 + q) ^ ((2 * pxl + kw) & 7));
        half8 bf[7];
#pragma unroll
        for (int nt = 0; nt < 7; ++nt) {
          int hx = 2 * (8 * nt + pxl) + kw;
          bf[nt] = *(const half8*)&hs[rbase + hx * 64 + gsw];
        }
#pragma unroll
        for (int mt = 0; mt < 2; ++mt) {
#pragma unroll
          for (int nt = 0; nt < 7; ++nt)
            acc[mt][nt] = __builtin_amdgcn_mfma_f32_16x16x32_f16(
                afr[mt][kc], bf[nt], acc[mt][nt], 0, 0, 0);
        }
      }
    }
  }

#pragma unroll
  for (int mt = 0; mt < 2; ++mt) {
#pragma unroll
    for (int reg = 0; reg < 4; ++reg) {
      const int oc = 32 * w + 16 * mt + 4 * q + reg;
      const float bias = b2[oc];
      float s = 0.f;
#pragma unroll
      for (int nt = 0; nt < 7; ++nt) s += fmaxf(acc[mt][nt][reg] + bias, 0.f);
      s += __shfl_xor(s, 1);
      s += __shfl_xor(s, 2);
      s += __shfl_xor(s, 4);
      s += __shfl_xor(s, 8);
      if (n == 0) atomicAdd(&g[((size_t)e * 64 + b) * 128 + oc], s);
    }
  }
}

__global__ __launch_bounds__(64) void finale(
    const float* __restrict__ g,
    const float* __restrict__ t_wf, const float* __restrict__ t_bf,
    const float* __restrict__ f_wf, const float* __restrict__ f_bf,
    float* __restrict__ out)
{
  const int b = threadIdx.x;
  const float inv = 1.0f / 3136.0f;
  const float* gt = g + b * 128;
  const float* gf = g + (64 + b) * 128;
  float lt0 = t_bf[0], lt1 = t_bf[1];
  float lf0 = f_bf[0], lf1 = f_bf[1];
  for (int k = 0; k < 128; ++k) {
    float vt = gt[k] * inv;
    float vf = gf[k] * inv;
    lt0 = fmaf(vt, t_wf[2 * k],     lt0);
    lt1 = fmaf(vt, t_wf[2 * k + 1], lt1);
    lf0 = fmaf(vf, f_wf[2 * k],     lf0);
    lf1 = fmaf(vf, f_wf[2 * k + 1], lf1);
  }
  float m  = fmaxf(lt0, lt1);
  float e0 = expf(lt0 - m), e1 = expf(lt1 - m);
  float conf = fmaxf(e0, e1) / (e0 + e1);
  bool use2 = (conf <= 0.9f);
  out[2 * b]     = use2 ? 0.7f * lt0 + 0.3f * lf0 : lt0;
  out[2 * b + 1] = use2 ? 0.7f * lt1 + 0.3f * lf1 : lt1;
  unsigned long long mask = __ballot(use2);
  if (b == 0) out[128] = (float)__popcll(mask) * (1.0f / 64.0f);
}

// ---------------- fallback (ws too small): round-1 fused fp32 ----------------
__global__ __launch_bounds__(256) void transpose_w2(
    const float* __restrict__ w2_t, const float* __restrict__ w2_f,
    float* __restrict__ w2t) {
  int idx = blockIdx.x * 256 + threadIdx.x;
  int e = idx / 73728;
  int r = idx - e * 73728;
  int k = r >> 7, oc = r & 127;
  const float* src = e ? w2_f : w2_t;
  w2t[idx] = src[oc * 576 + k];
}

__global__ __launch_bounds__(256, 3) void fused_expert(
    const float* __restrict__ x,
    const float* __restrict__ w1_t, const float* __restrict__ b1_t,
    const float* __restrict__ b2_t,
    const float* __restrict__ w1_f, const float* __restrict__ b1_f,
    const float* __restrict__ b2_f,
    const float* __restrict__ w2t_all, float* __restrict__ g)
{
  const int tile = blockIdx.x, b = blockIdx.y, e = blockIdx.z;
  const int ty = tile >> 1, tx = tile & 1;
  const float* w1  = e ? w1_f : w1_t;
  const float* b1  = e ? b1_f : b1_t;
  const float* b2  = e ? b2_f : b2_t;
  const float* w2t = w2t_all + e * 73728;
  __shared__ float x_s[3 * 19 * 116];
  __shared__ float h1_s[8 * 9 * 58];
  __shared__ float w1_s[1728];
  const int tid = threadIdx.x;
  {
    const float* xb = x + (size_t)b * 150528;
    const int xr0 = ty * 16, xc0 = tx * 112;
    for (int idx = tid; idx < 3 * 19 * 116; idx += 256) {
      int ic = idx / (19 * 116);
      int rem = idx - ic * (19 * 116);
      int r = rem / 116, cc = rem - r * 116;
      int xr = xr0 + r, xc = xc0 + cc;
      float v = 0.f;
      if (xr < 224 && xc < 224 && cc < 115) v = xb[(ic * 224 + xr) * 224 + xc];
      x_s[idx] = v;
    }
    for (int idx = tid; idx < 1728; idx += 256) w1_s[idx] = w1[idx];
  }
  const int ocg = tid >> 4, posg = tid & 15;
  int pbase[7];
#pragma unroll
  for (int j = 0; j < 7; ++j) {
    int p = posg + 16 * j, py = p / 28, px = p - py * 28;
    pbase[j] = py * 2 * 58 + px * 2;
  }
  float acc[7][8];
#pragma unroll
  for (int j = 0; j < 7; ++j)
#pragma unroll
    for (int i = 0; i < 8; ++i) acc[j][i] = 0.f;
  const int hc_l = tid >> 5, l32 = tid & 31;
  for (int c = 0; c < 8; ++c) {
    __syncthreads();
    {
      const int hc = c * 8 + hc_l;
      const float bias = b1[hc];
      float wr[27];
#pragma unroll
      for (int qq = 0; qq < 27; ++qq) wr[qq] = w1_s[hc * 27 + qq];
      for (int p = l32; p < 513; p += 32) {
        int hy = p / 57, hx = p - hy * 57;
        float a = bias;
#pragma unroll
        for (int ic = 0; ic < 3; ++ic)
#pragma unroll
          for (int kh = 0; kh < 3; ++kh) {
            const float* row = &x_s[ic * (19 * 116) + (2 * hy + kh) * 116 + 2 * hx];
            a = fmaf(row[0], wr[ic * 9 + kh * 3 + 0], a);
            a = fmaf(row[1], wr[ic * 9 + kh * 3 + 1], a);
            a = fmaf(row[2], wr[ic * 9 + kh * 3 + 2], a);
          }
        float v = fmaxf(a, 0.f);
        int hy_g = ty * 8 + hy, hx_g = tx * 56 + hx;
        if (hy_g >= 112 || hx_g >= 112) v = 0.f;
        h1_s[hc_l * 522 + hy * 58 + hx] = v;
      }
    }
    __syncthreads();
    for (int ic_l = 0; ic_l < 8; ++ic_l) {
#pragma unroll
      for (int kh = 0; kh < 3; ++kh)
#pragma unroll
        for (int kw = 0; kw < 3; ++kw) {
          const int k = (c * 8 + ic_l) * 9 + kh * 3 + kw;
          const float4 wA = *(const float4*)(w2t + k * 128 + ocg * 8);
          const float4 wB = *(const float4*)(w2t + k * 128 + ocg * 8 + 4);
          const float* hp = &h1_s[ic_l * 522 + kh * 58 + kw];
#pragma unroll
          for (int j = 0; j < 7; ++j) {
            float h = hp[pbase[j]];
            acc[j][0] = fmaf(wA.x, h, acc[j][0]);
            acc[j][1] = fmaf(wA.y, h, acc[j][1]);
            acc[j][2] = fmaf(wA.z, h, acc[j][2]);
            acc[j][3] = fmaf(wA.w, h, acc[j][3]);
            acc[j][4] = fmaf(wB.x, h, acc[j][4]);
            acc[j][5] = fmaf(wB.y, h, acc[j][5]);
            acc[j][6] = fmaf(wB.z, h, acc[j][6]);
            acc[j][7] = fmaf(wB.w, h, acc[j][7]);
          }
        }
    }
  }
  __syncthreads();
  float* red = x_s;
#pragma unroll
  for (int i = 0; i < 8; ++i) {
    float bb = b2[ocg * 8 + i];
    float t = 0.f;
#pragma unroll
    for (int j = 0; j < 7; ++j) t += fmaxf(acc[j][i] + bb, 0.f);
    red[posg * 129 + ocg * 8 + i] = t;
  }
  __syncthreads();
  if (tid < 128) {
    float t = 0.f;
#pragma unroll
    for (int pg = 0; pg < 16; ++pg) t += red[pg * 129 + tid];
    atomicAdd(&g[(e * 64 + b) * 128 + tid], t);
  }
}

extern "C" void kernel_launch(void* const* d_in, const int* in_sizes, int n_in,
                              void* d_out, int out_size, void* d_ws, size_t ws_size,
                              hipStream_t stream) {
  const float* x    = (const float*)d_in[0];
  const float* t_w1 = (const float*)d_in[1];
  const float* t_b1 = (const float*)d_in[2];
  const float* t_w2 = (const float*)d_in[3];
  const float* t_b2 = (const float*)d_in[4];
  const float* t_wf = (const float*)d_in[5];
  const float* t_bf = (const float*)d_in[6];
  const float* f_w1 = (const float*)d_in[7];
  const float* f_b1 = (const float*)d_in[8];
  const float* f_w2 = (const float*)d_in[9];
  const float* f_b2 = (const float*)d_in[10];
  const float* f_wf = (const float*)d_in[11];
  const float* f_bf = (const float*)d_in[12];
  float* out = (float*)d_out;
  char* ws = (char*)d_ws;

  if (ws_size >= WS_NEED) {
    float*  gbuf   = (float*)(ws + G_OFF);
    ushort* w2frag = (ushort*)(ws + W2B_OFF);
    ushort* w1f    = (ushort*)(ws + W1F_OFF);
    hipMemsetAsync(gbuf, 0, 2 * 64 * 128 * sizeof(float), stream);
    prep_new<<<592, 256, 0, stream>>>(t_w2, f_w2, t_w1, f_w1, ws);
    fused12<<<dim3(28, 64, 2), 256, 0, stream>>>(
        x, w1f, w2frag, t_b1, f_b1, t_b2, f_b2, gbuf);
    finale<<<1, 64, 0, stream>>>(gbuf, t_wf, t_bf, f_wf, f_bf, out);
  } else {
    float* w2t = (float*)ws;
    float* g2  = (float*)(ws + 589824);
    hipMemsetAsync(g2, 0, 2 * 64 * 128 * sizeof(float), stream);
    transpose_w2<<<576, 256, 0, stream>>>(t_w2, f_w2, w2t);
    fused_expert<<<dim3(28, 64, 2), 256, 0, stream>>>(
        x, t_w1, t_b1, t_b2, f_w1, f_b1, f_b2, w2t, g2);
    finale<<<1, 64, 0, stream>>>(g2, t_wf, t_bf, f_wf, f_bf, out);
  }
}